// Round 11
// baseline (140.605 us; speedup 1.0000x reference)
//
#include <hip/hip_runtime.h>
#include <math.h>

#define BB 16
#define AA 128
#define NNB 127
#define FF 128
#define GG 25

typedef __attribute__((ext_vector_type(8))) short bf16x8;
typedef __attribute__((ext_vector_type(4))) float f32x4;
typedef unsigned short ushort_t;

__device__ __forceinline__ float ssp_f(float x) {
    return fmaxf(x, 0.f) + log1pf(__expf(-fabsf(x))) - 0.6931471805599453f;
}

// softplus(x)-ln2 with poly log1p: 1 trans op. |err| <= ~1e-5
__device__ __forceinline__ float ssp_fast(float x) {
    float e = __expf(-fabsf(x));
    float p = fmaf(e, 0.03215845f, -0.13606275f);
    p = fmaf(e, p, 0.28947478f);
    p = fmaf(e, p, -0.49190896f);
    p = fmaf(e, p, 0.99949556f);
    return fmaxf(x, 0.f) + e * p - 0.6931471805599453f;
}

__device__ __forceinline__ ushort_t f2bf(float f) {
    unsigned int u = __float_as_uint(f);
    unsigned int r = (u + 0x7fffu + ((u >> 16) & 1u)) >> 16;
    return (ushort_t)r;
}

__device__ __forceinline__ unsigned int pack2bf(float lo, float hi) {
    return (unsigned int)f2bf(lo) | ((unsigned int)f2bf(hi) << 16);
}

// ---- prep: W1T bf16 [3][128f][32g]; W2 fragment-ordered bf16 ----
__global__ __launch_bounds__(256) void k_prep(const float* __restrict__ W1,
                                              const float* __restrict__ W2,
                                              ushort_t* __restrict__ w1t,
                                              ushort_t* __restrict__ w2f) {
    int i = blockIdx.x * 256 + threadIdx.x;
    if (i < 3 * 128 * 32) {
        int l = i >> 12, rem = i & 4095, f = rem >> 5, g = rem & 31;
        float v = (g < GG) ? W1[l * GG * FF + g * FF + f] : 0.f;
        w1t[i] = f2bf(v);
    }
    if (i < 3 * 16384) {
        // fragment-ordered: unit u = ((ks*8 + wcft)*64 + lane), 8 bf16 each.
        int l = i >> 14, e = i & 16383;
        int u = e >> 3, j = e & 7;
        int ks = u >> 9, rem = u & 511;
        int wcft = rem >> 6, lane = rem & 63;
        int f = (wcft >> 1) * 32 + (wcft & 1) * 16 + (lane & 15);
        int k = ks * 32 + (lane >> 4) * 8 + j;
        w2f[i] = f2bf(W2[l * 16384 + k * 128 + f]);
    }
}

// ---- x init ----
__global__ __launch_bounds__(256) void k_init_x(const float* __restrict__ emb,
                                                const int* __restrict__ z,
                                                float* __restrict__ x) {
    int i = blockIdx.x * 256 + threadIdx.x;
    if (i < BB * AA * FF) {
        int row = i >> 7, f = i & 127;
        x[i] = emb[z[row] * FF + f];
    }
}

// ---- y = x @ W (fp32), 4 rows per block ----
__global__ __launch_bounds__(128) void k_y(const float* __restrict__ x,
                                           const float* __restrict__ W,
                                           float* __restrict__ y) {
    int row0 = blockIdx.x << 2, t = threadIdx.x;
    __shared__ float xs[4][FF];
#pragma unroll
    for (int r = 0; r < 4; ++r) xs[r][t] = x[(row0 + r) * FF + t];
    __syncthreads();
    float acc[4] = {0.f, 0.f, 0.f, 0.f};
#pragma unroll 4
    for (int k = 0; k < FF; ++k) {
        float wv = W[k * FF + t];
        acc[0] = fmaf(xs[0][k], wv, acc[0]);
        acc[1] = fmaf(xs[1][k], wv, acc[1]);
        acc[2] = fmaf(xs[2][k], wv, acc[2]);
        acc[3] = fmaf(xs[3][k], wv, acc[3]);
    }
#pragma unroll
    for (int r = 0; r < 4; ++r) y[(row0 + r) * FF + t] = acc[r];
}

// LDS layout (dynamic, 34304 B):
//  [0,32768)      h bf16 [128n][128f], swizzled: byte = n*256 + ((f*2) ^ ((n&7)<<4))
//  [0,4096)       (post-phase2 alias) red: 8 waves x 128 f32, swizzled
//  [4096,4608)    agg_s f32[128]; [4608,5120) ts_s f32[128]; [5120,5632) xn_s f32[128]
//  [32768,33280)  cm f32[128]; [33280,33792) nbr i32[128]; [33792,34304) r f32[128]
#define SMEM_BYTES 34304

__global__ __launch_bounds__(512, 6) void k_cfconv(
    const float* __restrict__ positions, const float* __restrict__ cell,
    const float* __restrict__ cell_offset, const float* __restrict__ nmask,
    const int* __restrict__ neighbors,
    const ushort_t* __restrict__ w1t, const float* __restrict__ b1,
    const ushort_t* __restrict__ w2f, const float* __restrict__ b2,
    const float* __restrict__ y,
    // fused FFN tail:
    float* __restrict__ x_io,
    const float* __restrict__ Wf_g, const float* __restrict__ bf_g,
    const float* __restrict__ Wd_g, const float* __restrict__ bd_g,
    const float* __restrict__ win_g,   // in2f_W of NEXT layer, or null
    float* __restrict__ y_out,         // next-layer y buffer
    float* __restrict__ outp, int wout) {
    extern __shared__ char smem[];
    float* cm_s = (float*)(smem + 32768);
    int* nbr_s = (int*)(smem + 33280);
    float* r_s = (float*)(smem + 33792);
    float* red_s = (float*)smem;
    float* agg_s = (float*)(smem + 4096);
    float* ts_s = (float*)(smem + 4608);
    float* xn_s = (float*)(smem + 5120);

    const int row = blockIdx.x;
    const int b = row >> 7;
    const int t = threadIdx.x;
    const int lane = t & 63, w = t >> 6;       // 8 waves
    const int l15 = lane & 15, l4 = lane >> 4;
    const int wr = w >> 2, wc = w & 3;

    // -- phase 0a: distances + cutoff --
    if (t < NNB) {
        int nb = neighbors[row * NNB + t];
        nbr_s[t] = nb;
        float px = positions[row * 3 + 0], py = positions[row * 3 + 1], pz = positions[row * 3 + 2];
        int nrow = b * AA + nb;
        float qx = positions[nrow * 3 + 0], qy = positions[nrow * 3 + 1], qz = positions[nrow * 3 + 2];
        const float* co = cell_offset + (size_t)row * NNB * 3 + (size_t)t * 3;
        const float* cl = cell + b * 9;
        float c0 = co[0], c1 = co[1], c2 = co[2];
        float ox = c0 * cl[0] + c1 * cl[3] + c2 * cl[6];
        float oy = c0 * cl[1] + c1 * cl[4] + c2 * cl[7];
        float oz = c0 * cl[2] + c1 * cl[5] + c2 * cl[8];
        float dx = qx - px + ox, dy = qy - py + oy, dz = qz - pz + oz;
        float d2 = dx * dx + dy * dy + dz * dz;
        float mk = nmask[row * NNB + t];
        float r = (mk > 0.f) ? sqrtf(d2) : 0.f;
        r_s[t] = r;
        float Cc = 0.5f * (__cosf(r * (3.14159265358979323846f / 5.0f)) + 1.f);
        Cc = (r < 5.0f) ? Cc : 0.f;
        cm_s[t] = Cc * mk;
    } else if (t == NNB) {
        cm_s[NNB] = 0.f; nbr_s[NNB] = 0; r_s[NNB] = 1e9f;
    }
    __syncthreads();   // (1) r_s, nbr_s ready

    // -- phase 1: fij in registers; D[f][n] = W1T * fijT; ssp; b64 swizzled h write --
    {
        const int nrow = (w << 4) + l15;
        const float rv = r_s[nrow];
        const float width = 5.0f / (GG - 1);
        const float coeff = -0.5f / (width * width);
        bf16x8 fb;
#pragma unroll
        for (int j = 0; j < 8; ++j) {
            int g = (l4 << 3) + j;
            float d = rv - g * width;
            float v = (g < GG && nrow < NNB) ? __expf(coeff * d * d) : 0.f;
            fb[j] = (short)f2bf(v);
        }
        const int base = nrow * 256;
        const int sw = (nrow & 7) << 4;
#pragma unroll
        for (int ft = 0; ft < 8; ++ft) {
            bf16x8 aw = *(const bf16x8*)(w1t + ((ft << 4) + l15) * 32 + (l4 << 3));
            const int f0 = (ft << 4) + (l4 << 2);
            f32x4 c0 = *(const f32x4*)(b1 + f0);
            f32x4 d = __builtin_amdgcn_mfma_f32_16x16x32_bf16(aw, fb, c0, 0, 0, 0);
            unsigned long long pk =
                (unsigned long long)pack2bf(ssp_fast(d[0]), ssp_fast(d[1])) |
                ((unsigned long long)pack2bf(ssp_fast(d[2]), ssp_fast(d[3])) << 32);
            *(unsigned long long*)(smem + base + ((f0 << 1) ^ sw)) = pk;
        }
    }

    // issue first W2 fragment loads before the barrier (independent of LDS)
#define W2LD(ks, ft) (*(const bf16x8*)(w2f + (((((ks) << 3) + (wc << 1) + (ft)) << 6) + lane) * 8))
    bf16x8 wb0 = W2LD(0, 0), wb1 = W2LD(0, 1);
    __syncthreads();   // (2) h ready

    // -- phase 2: wave (wr,wc) = 64n x 32f; B-frags prefetched from global/L2 --
    f32x4 acc[4][2];
#pragma unroll
    for (int mi = 0; mi < 4; ++mi)
#pragma unroll
        for (int ft = 0; ft < 2; ++ft) {
            float b2v = b2[(wc << 5) + (ft << 4) + l15];
            f32x4 c0 = {b2v, b2v, b2v, b2v};
            acc[mi][ft] = c0;
        }
#pragma unroll
    for (int ks = 0; ks < 4; ++ks) {
        bf16x8 wn0, wn1;
        if (ks < 3) { wn0 = W2LD(ks + 1, 0); wn1 = W2LD(ks + 1, 1); }
        bf16x8 ha[4];
#pragma unroll
        for (int mi = 0; mi < 4; ++mi) {
            int n = (wr << 6) + (mi << 4) + l15;
            ha[mi] = *(const bf16x8*)(smem + n * 256 + ((((ks << 2) + l4) << 4) ^ ((n & 7) << 4)));
        }
#pragma unroll
        for (int mi = 0; mi < 4; ++mi) {
            acc[mi][0] = __builtin_amdgcn_mfma_f32_16x16x32_bf16(ha[mi], wb0, acc[mi][0], 0, 0, 0);
            acc[mi][1] = __builtin_amdgcn_mfma_f32_16x16x32_bf16(ha[mi], wb1, acc[mi][1], 0, 0, 0);
        }
        if (ks < 3) { wb0 = wn0; wb1 = wn1; }
    }
#undef W2LD
    __syncthreads();   // (3) all h reads done; red region safe

    // -- epilogue: gather y rows directly from L2; part += y * (acc * cm) --
    float part0 = 0.f, part1 = 0.f;
    const float* ybase = y + ((size_t)(b * AA) << 7) + (wc << 5) + l15;
#pragma unroll
    for (int mi = 0; mi < 4; ++mi) {
        float yv0[4], yv1[4], cmv[4];
#pragma unroll
        for (int r = 0; r < 4; ++r) {
            int n = (wr << 6) + (mi << 4) + (l4 << 2) + r;
            int nb = nbr_s[n];
            cmv[r] = cm_s[n];
            const float* yr = ybase + ((size_t)nb << 7);
            yv0[r] = yr[0];
            yv1[r] = yr[16];
        }
#pragma unroll
        for (int r = 0; r < 4; ++r) {
            part0 = fmaf(yv0[r], acc[mi][0][r] * cmv[r], part0);
            part1 = fmaf(yv1[r], acc[mi][1][r] * cmv[r], part1);
        }
    }
    {
        int xg = l4 << 3;
        red_s[(w << 7) + (l4 << 5) + (l15 ^ xg)] = part0;
        red_s[(w << 7) + (l4 << 5) + ((16 + l15) ^ xg)] = part1;
    }
    __syncthreads();   // (4)
    if (t < FF) {
        int wcf = t >> 5, fl = t & 31;
        float s = 0.f;
#pragma unroll
        for (int wr2 = 0; wr2 < 2; ++wr2)
#pragma unroll
            for (int g = 0; g < 4; ++g)
                s += red_s[(((wr2 << 2) + wcf) << 7) + (g << 5) + (fl ^ (g << 3))];
        agg_s[t] = s;
    }
    __syncthreads();   // (5) agg_s ready

    // ---- fused FFN tail: 3 wave-parallel fp32 GEMVs (row-local) ----
    const int f = (w << 4) + l15;
    // G1: ts = ssp(agg @ Wf + bf)
    {
        float p = 0.f;
        const float* Wcol = Wf_g + f;
#pragma unroll 8
        for (int i = 0; i < 32; ++i) {
            int k = (i << 2) + l4;
            p = fmaf(agg_s[k], Wcol[(size_t)k << 7], p);
        }
        p += __shfl_xor(p, 16);
        p += __shfl_xor(p, 32);
        if (l4 == 0) ts_s[f] = ssp_f(p + bf_g[f]);
    }
    __syncthreads();   // (6) ts ready
    // G2: xn = x + ts @ Wd + bd
    {
        float p = 0.f;
        const float* Wcol = Wd_g + f;
#pragma unroll 8
        for (int i = 0; i < 32; ++i) {
            int k = (i << 2) + l4;
            p = fmaf(ts_s[k], Wcol[(size_t)k << 7], p);
        }
        p += __shfl_xor(p, 16);
        p += __shfl_xor(p, 32);
        if (l4 == 0) {
            size_t gi = ((size_t)row << 7) + f;
            float xn = x_io[gi] + p + bd_g[f];
            x_io[gi] = xn;
            if (wout) outp[gi] = xn;
            xn_s[f] = xn;
        }
    }
    if (win_g) {
        __syncthreads();   // (7) xn ready
        // G3: y_next = xn @ Win_next
        float p = 0.f;
        const float* Wcol = win_g + f;
#pragma unroll 8
        for (int i = 0; i < 32; ++i) {
            int k = (i << 2) + l4;
            p = fmaf(xn_s[k], Wcol[(size_t)k << 7], p);
        }
        p += __shfl_xor(p, 16);
        p += __shfl_xor(p, 32);
        if (l4 == 0) y_out[((size_t)row << 7) + f] = p;
    }
}

extern "C" void kernel_launch(void* const* d_in, const int* in_sizes, int n_in,
                              void* d_out, int out_size, void* d_ws, size_t ws_size,
                              hipStream_t stream) {
    const float* positions   = (const float*)d_in[0];
    const float* cell        = (const float*)d_in[1];
    const float* cell_offset = (const float*)d_in[2];
    const float* nmask       = (const float*)d_in[3];
    const float* emb         = (const float*)d_in[4];
    const float* filt_W1     = (const float*)d_in[5];
    const float* filt_b1     = (const float*)d_in[6];
    const float* filt_W2     = (const float*)d_in[7];
    const float* filt_b2     = (const float*)d_in[8];
    const float* in2f_W      = (const float*)d_in[9];
    const float* f2out_W     = (const float*)d_in[10];
    const float* f2out_b     = (const float*)d_in[11];
    const float* dense_W     = (const float*)d_in[12];
    const float* dense_b     = (const float*)d_in[13];
    const int* atomic_numbers = (const int*)d_in[14];
    const int* neighbors      = (const int*)d_in[15];
    float* out = (float*)d_out;

    float* x    = (float*)d_ws;                        // 262144 f32
    float* yb0  = x + BB * AA * FF;                    // 262144 f32
    float* yb1  = yb0 + BB * AA * FF;                  // 262144 f32
    ushort_t* w1t = (ushort_t*)(yb1 + BB * AA * FF);   // 12288 u16
    ushort_t* w2f = w1t + 3 * 128 * 32;                // 49152 u16

    k_prep<<<192, 256, 0, stream>>>(filt_W1, filt_W2, w1t, w2f);
    k_init_x<<<(BB * AA * FF + 255) / 256, 256, 0, stream>>>(emb, atomic_numbers, x);
    k_y<<<BB * AA / 4, FF, 0, stream>>>(x, in2f_W, yb0);   // y0 = x @ in2f_W[0]

    float* ybufs[2] = {yb0, yb1};
    for (int l = 0; l < 3; ++l) {
        const float* yin = ybufs[l & 1];
        float* yout = ybufs[(l + 1) & 1];
        const float* win = (l < 2) ? (in2f_W + (size_t)(l + 1) * FF * FF) : nullptr;
        k_cfconv<<<BB * AA, 512, SMEM_BYTES, stream>>>(
            positions, cell, cell_offset, nmask, neighbors,
            w1t + (size_t)l * 128 * 32, filt_b1 + (size_t)l * FF,
            w2f + (size_t)l * 16384, filt_b2 + (size_t)l * FF,
            yin,
            x,
            f2out_W + (size_t)l * FF * FF, f2out_b + (size_t)l * FF,
            dense_W + (size_t)l * FF * FF, dense_b + (size_t)l * FF,
            win, yout, out, (l == 2) ? 1 : 0);
    }
}

// Round 12
// 127.024 us; speedup vs baseline: 1.1069x; 1.1069x over previous
//
#include <hip/hip_runtime.h>
#include <math.h>

#define BB 16
#define AA 128
#define NNB 127
#define FF 128
#define GG 25

typedef __attribute__((ext_vector_type(8))) short bf16x8;
typedef __attribute__((ext_vector_type(4))) float f32x4;
typedef unsigned short ushort_t;

__device__ __forceinline__ float ssp_f(float x) {
    return fmaxf(x, 0.f) + log1pf(__expf(-fabsf(x))) - 0.6931471805599453f;
}

// softplus(x)-ln2 with poly log1p: 1 trans op. |err| <= ~1e-5
__device__ __forceinline__ float ssp_fast(float x) {
    float e = __expf(-fabsf(x));
    float p = fmaf(e, 0.03215845f, -0.13606275f);
    p = fmaf(e, p, 0.28947478f);
    p = fmaf(e, p, -0.49190896f);
    p = fmaf(e, p, 0.99949556f);
    return fmaxf(x, 0.f) + e * p - 0.6931471805599453f;
}

__device__ __forceinline__ ushort_t f2bf(float f) {
    unsigned int u = __float_as_uint(f);
    unsigned int r = (u + 0x7fffu + ((u >> 16) & 1u)) >> 16;
    return (ushort_t)r;
}

__device__ __forceinline__ float bf2f(ushort_t h) {
    return __uint_as_float(((unsigned int)h) << 16);
}

// round-half-up bf16 pair pack: 2 adds + 1 v_perm (vs ~10 ops RNE). err <= 0.5 ulp.
__device__ __forceinline__ unsigned int pack2bf_rhu(float lo, float hi) {
    return __builtin_amdgcn_perm(__float_as_uint(hi) + 0x8000u,
                                 __float_as_uint(lo) + 0x8000u, 0x07060302u);
}

// ---- geometry precompute (once for all 3 layers): r, cm = cutoff*mask ----
__global__ __launch_bounds__(256) void k_geom(const float* __restrict__ positions,
                                              const float* __restrict__ cell,
                                              const float* __restrict__ cell_offset,
                                              const float* __restrict__ nmask,
                                              const int* __restrict__ neighbors,
                                              float* __restrict__ r_g,
                                              float* __restrict__ cm_g) {
    int i = blockIdx.x * 256 + threadIdx.x;   // over 2048*128
    if (i >= BB * AA * 128) return;
    int row = i >> 7, n = i & 127;
    if (n < NNB) {
        int b = row >> 7;
        int nb = neighbors[row * NNB + n];
        float px = positions[row * 3 + 0], py = positions[row * 3 + 1], pz = positions[row * 3 + 2];
        int nrow = b * AA + nb;
        float qx = positions[nrow * 3 + 0], qy = positions[nrow * 3 + 1], qz = positions[nrow * 3 + 2];
        const float* co = cell_offset + (size_t)row * NNB * 3 + (size_t)n * 3;
        const float* cl = cell + b * 9;
        float c0 = co[0], c1 = co[1], c2 = co[2];
        float ox = c0 * cl[0] + c1 * cl[3] + c2 * cl[6];
        float oy = c0 * cl[1] + c1 * cl[4] + c2 * cl[7];
        float oz = c0 * cl[2] + c1 * cl[5] + c2 * cl[8];
        float dx = qx - px + ox, dy = qy - py + oy, dz = qz - pz + oz;
        float d2 = dx * dx + dy * dy + dz * dz;
        float mk = nmask[row * NNB + n];
        float r = (mk > 0.f) ? sqrtf(d2) : 0.f;
        float Cc = 0.5f * (__cosf(r * (3.14159265358979323846f / 5.0f)) + 1.f);
        Cc = (r < 5.0f) ? Cc : 0.f;
        r_g[i] = r;
        cm_g[i] = Cc * mk;
    } else {
        r_g[i] = 1e9f;
        cm_g[i] = 0.f;
    }
}

// ---- prep: W1T bf16; W2 fragment-ordered bf16; ffn weights hi/lo split bf16 [f][k] ----
__global__ __launch_bounds__(256) void k_prep(const float* __restrict__ W1,
                                              const float* __restrict__ W2,
                                              const float* __restrict__ Win,
                                              const float* __restrict__ Wf,
                                              const float* __restrict__ Wd,
                                              ushort_t* __restrict__ w1t,
                                              ushort_t* __restrict__ w2f,
                                              ushort_t* __restrict__ whi,
                                              ushort_t* __restrict__ wlo) {
    int i = blockIdx.x * 256 + threadIdx.x;
    if (i < 3 * 128 * 32) {
        int l = i >> 12, rem = i & 4095, f = rem >> 5, g = rem & 31;
        float v = (g < GG) ? W1[l * GG * FF + g * FF + f] : 0.f;
        w1t[i] = f2bf(v);
    }
    if (i < 3 * 16384) {
        // fragment-ordered: unit u = ((ks*8 + wcft)*64 + lane), 8 bf16 each.
        int l = i >> 14, e = i & 16383;
        int u = e >> 3, j = e & 7;
        int ks = u >> 9, rem = u & 511;
        int wcft = rem >> 6, lane = rem & 63;
        int f = (wcft >> 1) * 32 + (wcft & 1) * 16 + (lane & 15);
        int k = ks * 32 + (lane >> 4) * 8 + j;
        w2f[i] = f2bf(W2[l * 16384 + k * 128 + f]);
    }
    if (i < 9 * 16384) {
        int m = i / 49152;
        int rem = i - m * 49152;
        int l = rem >> 14;
        int rk = rem & 16383;
        int f = rk >> 7, k = rk & 127;
        const float* src = (m == 0) ? Win : ((m == 1) ? Wf : Wd);
        float v = src[l * 16384 + k * 128 + f];
        ushort_t h = f2bf(v);
        whi[i] = h;
        wlo[i] = f2bf(v - bf2f(h));
    }
}

// ---- x init ----
__global__ __launch_bounds__(256) void k_init_x(const float* __restrict__ emb,
                                                const int* __restrict__ z,
                                                float* __restrict__ x) {
    int i = blockIdx.x * 256 + threadIdx.x;
    if (i < BB * AA * FF) {
        int row = i >> 7, f = i & 127;
        x[i] = emb[z[row] * FF + f];
    }
}

// ---- fused row-GEMM kernel: G1 ts=ssp(agg@Wf+bf); G2 xn=x+ts@Wd+bd; G3 y=xn@Win ----
__global__ __launch_bounds__(512) void k_ffn(
    const float* __restrict__ agg, const float* __restrict__ x_in,
    float* __restrict__ x_out, float* __restrict__ y, float* __restrict__ out,
    const ushort_t* __restrict__ wfh, const ushort_t* __restrict__ wfl, const float* __restrict__ bfv_g,
    const ushort_t* __restrict__ wdh, const ushort_t* __restrict__ wdl, const float* __restrict__ bdv_g,
    const ushort_t* __restrict__ wih, const ushort_t* __restrict__ wil,
    int mode) {
    __shared__ ushort_t tsh[8][136];
    __shared__ ushort_t tsl[8][136];
    const int t = threadIdx.x;
    const int lane = t & 63, w = t >> 6;
    const int l15 = lane & 15, l4 = lane >> 4;
    const int r0 = blockIdx.x << 3;
    const int fcol = (w << 4) + l15;

    bf16x8 Ah[4], Al[4];

    auto loadA_global = [&](const float* __restrict__ M) {
#pragma unroll
        for (int ks = 0; ks < 4; ++ks) {
            float v[8];
            if (l15 < 8) {
                const float4* p = (const float4*)(M + ((size_t)(r0 + l15) << 7) + (ks << 5) + (l4 << 3));
                float4 a = p[0], b = p[1];
                v[0] = a.x; v[1] = a.y; v[2] = a.z; v[3] = a.w;
                v[4] = b.x; v[5] = b.y; v[6] = b.z; v[7] = b.w;
            } else {
#pragma unroll
                for (int j = 0; j < 8; ++j) v[j] = 0.f;
            }
#pragma unroll
            for (int j = 0; j < 8; ++j) {
                ushort_t h = f2bf(v[j]);
                Ah[ks][j] = (short)h;
                Al[ks][j] = (short)f2bf(v[j] - bf2f(h));
            }
        }
    };
    auto loadA_lds = [&]() {
#pragma unroll
        for (int ks = 0; ks < 4; ++ks) {
            if (l15 < 8) {
                const char* base = (const char*)&tsh[l15][0] + (ks << 6) + (l4 << 4);
                Ah[ks] = *(const bf16x8*)base;
                const char* basel = (const char*)&tsl[l15][0] + (ks << 6) + (l4 << 4);
                Al[ks] = *(const bf16x8*)basel;
            } else {
#pragma unroll
                for (int j = 0; j < 8; ++j) { Ah[ks][j] = 0; Al[ks][j] = 0; }
            }
        }
    };

    if (mode & 1) {
        loadA_global(agg);
        float bfv = bfv_g[fcol];
        f32x4 acc = {bfv, bfv, bfv, bfv};
#pragma unroll
        for (int ks = 0; ks < 4; ++ks) {
            const bf16x8 Bh = *(const bf16x8*)(wfh + ((size_t)fcol << 7) + (ks << 5) + (l4 << 3));
            const bf16x8 Bl = *(const bf16x8*)(wfl + ((size_t)fcol << 7) + (ks << 5) + (l4 << 3));
            acc = __builtin_amdgcn_mfma_f32_16x16x32_bf16(Al[ks], Bh, acc, 0, 0, 0);
            acc = __builtin_amdgcn_mfma_f32_16x16x32_bf16(Ah[ks], Bl, acc, 0, 0, 0);
            acc = __builtin_amdgcn_mfma_f32_16x16x32_bf16(Ah[ks], Bh, acc, 0, 0, 0);
        }
#pragma unroll
        for (int reg = 0; reg < 4; ++reg) {
            int r = (l4 << 2) + reg;
            if (r < 8) {
                float v = ssp_f(acc[reg]);
                ushort_t h = f2bf(v);
                tsh[r][fcol] = h;
                tsl[r][fcol] = f2bf(v - bf2f(h));
            }
        }
        __syncthreads();
        loadA_lds();
        float bdv = bdv_g[fcol];
        f32x4 acc2 = {bdv, bdv, bdv, bdv};
#pragma unroll
        for (int ks = 0; ks < 4; ++ks) {
            const bf16x8 Bh = *(const bf16x8*)(wdh + ((size_t)fcol << 7) + (ks << 5) + (l4 << 3));
            const bf16x8 Bl = *(const bf16x8*)(wdl + ((size_t)fcol << 7) + (ks << 5) + (l4 << 3));
            acc2 = __builtin_amdgcn_mfma_f32_16x16x32_bf16(Al[ks], Bh, acc2, 0, 0, 0);
            acc2 = __builtin_amdgcn_mfma_f32_16x16x32_bf16(Ah[ks], Bl, acc2, 0, 0, 0);
            acc2 = __builtin_amdgcn_mfma_f32_16x16x32_bf16(Ah[ks], Bh, acc2, 0, 0, 0);
        }
        __syncthreads();
#pragma unroll
        for (int reg = 0; reg < 4; ++reg) {
            int r = (l4 << 2) + reg;
            if (r < 8) {
                size_t gi = ((size_t)(r0 + r) << 7) + fcol;
                float xn = x_in[gi] + acc2[reg];
                x_out[gi] = xn;
                if (mode & 4) out[gi] = xn;
                if (mode & 2) {
                    ushort_t h = f2bf(xn);
                    tsh[r][fcol] = h;
                    tsl[r][fcol] = f2bf(xn - bf2f(h));
                }
            }
        }
        if (mode & 2) __syncthreads();
    }
    if (mode & 2) {
        if (mode & 1) loadA_lds(); else loadA_global(x_in);
        f32x4 acc3 = {0.f, 0.f, 0.f, 0.f};
#pragma unroll
        for (int ks = 0; ks < 4; ++ks) {
            const bf16x8 Bh = *(const bf16x8*)(wih + ((size_t)fcol << 7) + (ks << 5) + (l4 << 3));
            const bf16x8 Bl = *(const bf16x8*)(wil + ((size_t)fcol << 7) + (ks << 5) + (l4 << 3));
            acc3 = __builtin_amdgcn_mfma_f32_16x16x32_bf16(Al[ks], Bh, acc3, 0, 0, 0);
            acc3 = __builtin_amdgcn_mfma_f32_16x16x32_bf16(Ah[ks], Bl, acc3, 0, 0, 0);
            acc3 = __builtin_amdgcn_mfma_f32_16x16x32_bf16(Ah[ks], Bh, acc3, 0, 0, 0);
        }
#pragma unroll
        for (int reg = 0; reg < 4; ++reg) {
            int r = (l4 << 2) + reg;
            if (r < 8) y[((size_t)(r0 + r) << 7) + fcol] = acc3[reg];
        }
    }
}

// LDS layout (dynamic, 34304 B):
//  [0,32768)      h bf16 [128n][128f], swizzled: byte = n*256 + ((f*2) ^ ((n&7)<<4))
//  [0,4096)       (post-phase2 alias) red: 8 waves x 128 f32, swizzled
//  [32768,33280)  cm f32[128]; [33280,33792) nbr i32[128]; [33792,34304) r f32[128]
#define SMEM_BYTES 34304

__global__ __launch_bounds__(512, 6) void k_cfconv(
    const float* __restrict__ r_g, const float* __restrict__ cm_g,
    const int* __restrict__ neighbors,
    const ushort_t* __restrict__ w1t, const float* __restrict__ b1,
    const ushort_t* __restrict__ w2f, const float* __restrict__ b2,
    const float* __restrict__ y, float* __restrict__ agg) {
    extern __shared__ char smem[];
    float* cm_s = (float*)(smem + 32768);
    int* nbr_s = (int*)(smem + 33280);
    float* r_s = (float*)(smem + 33792);
    float* red_s = (float*)smem;

    const int row = blockIdx.x;
    const int b = row >> 7;
    const int t = threadIdx.x;
    const int lane = t & 63, w = t >> 6;       // 8 waves
    const int l15 = lane & 15, l4 = lane >> 4;
    const int wr = w >> 2, wc = w & 3;

    // -- phase 0a: load precomputed geometry (coalesced) --
    if (t < 128) {
        r_s[t] = r_g[((size_t)row << 7) + t];
        cm_s[t] = cm_g[((size_t)row << 7) + t];
        nbr_s[t] = (t < NNB) ? neighbors[row * NNB + t] : 0;
    }
    __syncthreads();   // (1) r_s, cm_s, nbr_s ready

    // -- phase 1: fij in registers; D[f][n] = W1T * fijT; ssp; b64 swizzled h write --
    {
        const int nrow = (w << 4) + l15;
        const float rv = r_s[nrow];
        const float width = 5.0f / (GG - 1);
        const float coeff = -0.5f / (width * width);
        float fv[8];
#pragma unroll
        for (int j = 0; j < 8; ++j) {
            int g = (l4 << 3) + j;
            float d = rv - g * width;
            fv[j] = (g < GG) ? __expf(coeff * d * d) : 0.f;
        }
        bf16x8 fb;
        unsigned int* fbu = (unsigned int*)&fb;
        fbu[0] = pack2bf_rhu(fv[0], fv[1]);
        fbu[1] = pack2bf_rhu(fv[2], fv[3]);
        fbu[2] = pack2bf_rhu(fv[4], fv[5]);
        fbu[3] = pack2bf_rhu(fv[6], fv[7]);
        const int base = nrow * 256;
        const int sw = (nrow & 7) << 4;
#pragma unroll
        for (int ft = 0; ft < 8; ++ft) {
            bf16x8 aw = *(const bf16x8*)(w1t + ((ft << 4) + l15) * 32 + (l4 << 3));
            const int f0 = (ft << 4) + (l4 << 2);
            f32x4 c0 = *(const f32x4*)(b1 + f0);
            f32x4 d = __builtin_amdgcn_mfma_f32_16x16x32_bf16(aw, fb, c0, 0, 0, 0);
            unsigned int lo32 = pack2bf_rhu(ssp_fast(d[0]), ssp_fast(d[1]));
            unsigned int hi32 = pack2bf_rhu(ssp_fast(d[2]), ssp_fast(d[3]));
            unsigned long long pk = (unsigned long long)lo32 | ((unsigned long long)hi32 << 32);
            *(unsigned long long*)(smem + base + ((f0 << 1) ^ sw)) = pk;
        }
    }

    // issue first W2 fragment loads before the barrier (independent of LDS)
#define W2LD(ks, ft) (*(const bf16x8*)(w2f + (((((ks) << 3) + (wc << 1) + (ft)) << 6) + lane) * 8))
    bf16x8 wb0 = W2LD(0, 0), wb1 = W2LD(0, 1);
    __syncthreads();   // (2) h ready

    // -- phase 2: wave (wr,wc) = 64n x 32f; B-frags prefetched from global/L2 --
    f32x4 acc[4][2];
#pragma unroll
    for (int mi = 0; mi < 4; ++mi)
#pragma unroll
        for (int ft = 0; ft < 2; ++ft) {
            float b2v = b2[(wc << 5) + (ft << 4) + l15];
            f32x4 c0 = {b2v, b2v, b2v, b2v};
            acc[mi][ft] = c0;
        }
#pragma unroll
    for (int ks = 0; ks < 4; ++ks) {
        bf16x8 wn0, wn1;
        if (ks < 3) { wn0 = W2LD(ks + 1, 0); wn1 = W2LD(ks + 1, 1); }
        bf16x8 ha[4];
#pragma unroll
        for (int mi = 0; mi < 4; ++mi) {
            int n = (wr << 6) + (mi << 4) + l15;
            ha[mi] = *(const bf16x8*)(smem + n * 256 + ((((ks << 2) + l4) << 4) ^ ((n & 7) << 4)));
        }
#pragma unroll
        for (int mi = 0; mi < 4; ++mi) {
            acc[mi][0] = __builtin_amdgcn_mfma_f32_16x16x32_bf16(ha[mi], wb0, acc[mi][0], 0, 0, 0);
            acc[mi][1] = __builtin_amdgcn_mfma_f32_16x16x32_bf16(ha[mi], wb1, acc[mi][1], 0, 0, 0);
        }
        if (ks < 3) { wb0 = wn0; wb1 = wn1; }
    }
#undef W2LD
    __syncthreads();   // (3) all h reads done; red region safe

    // -- epilogue: gather y rows directly from L2; part += y * (acc * cm) --
    float part0 = 0.f, part1 = 0.f;
    const float* ybase = y + ((size_t)(b * AA) << 7) + (wc << 5) + l15;
#pragma unroll
    for (int mi = 0; mi < 4; ++mi) {
        float yv0[4], yv1[4], cmv[4];
#pragma unroll
        for (int r = 0; r < 4; ++r) {
            int n = (wr << 6) + (mi << 4) + (l4 << 2) + r;
            int nb = nbr_s[n];
            cmv[r] = cm_s[n];
            const float* yr = ybase + ((size_t)nb << 7);
            yv0[r] = yr[0];
            yv1[r] = yr[16];
        }
#pragma unroll
        for (int r = 0; r < 4; ++r) {
            part0 = fmaf(yv0[r], acc[mi][0][r] * cmv[r], part0);
            part1 = fmaf(yv1[r], acc[mi][1][r] * cmv[r], part1);
        }
    }
    {
        int xg = l4 << 3;
        red_s[(w << 7) + (l4 << 5) + (l15 ^ xg)] = part0;
        red_s[(w << 7) + (l4 << 5) + ((16 + l15) ^ xg)] = part1;
    }
    __syncthreads();   // (4)
    if (t < FF) {
        int wcf = t >> 5, fl = t & 31;
        float s = 0.f;
#pragma unroll
        for (int wr2 = 0; wr2 < 2; ++wr2)
#pragma unroll
            for (int g = 0; g < 4; ++g)
                s += red_s[(((wr2 << 2) + wcf) << 7) + (g << 5) + (fl ^ (g << 3))];
        agg[(size_t)row * FF + t] = s;
    }
}

extern "C" void kernel_launch(void* const* d_in, const int* in_sizes, int n_in,
                              void* d_out, int out_size, void* d_ws, size_t ws_size,
                              hipStream_t stream) {
    const float* positions   = (const float*)d_in[0];
    const float* cell        = (const float*)d_in[1];
    const float* cell_offset = (const float*)d_in[2];
    const float* nmask       = (const float*)d_in[3];
    const float* emb         = (const float*)d_in[4];
    const float* filt_W1     = (const float*)d_in[5];
    const float* filt_b1     = (const float*)d_in[6];
    const float* filt_W2     = (const float*)d_in[7];
    const float* filt_b2     = (const float*)d_in[8];
    const float* in2f_W      = (const float*)d_in[9];
    const float* f2out_W     = (const float*)d_in[10];
    const float* f2out_b     = (const float*)d_in[11];
    const float* dense_W     = (const float*)d_in[12];
    const float* dense_b     = (const float*)d_in[13];
    const int* atomic_numbers = (const int*)d_in[14];
    const int* neighbors      = (const int*)d_in[15];
    float* out = (float*)d_out;

    float* x    = (float*)d_ws;                        // 262144 f32
    float* yb   = x + BB * AA * FF;                    // 262144 f32
    float* agg  = yb + BB * AA * FF;                   // 262144 f32
    float* r_g  = agg + BB * AA * FF;                  // 262144 f32
    float* cm_g = r_g + BB * AA * 128;                 // 262144 f32
    ushort_t* w1t = (ushort_t*)(cm_g + BB * AA * 128); // 12288 u16
    ushort_t* w2f = w1t + 3 * 128 * 32;                // 49152 u16
    ushort_t* whi = w2f + 3 * 16384;                   // 147456 u16
    ushort_t* wlo = whi + 9 * 16384;                   // 147456 u16

    k_geom<<<(BB * AA * 128 + 255) / 256, 256, 0, stream>>>(positions, cell, cell_offset,
                                                            nmask, neighbors, r_g, cm_g);
    k_prep<<<576, 256, 0, stream>>>(filt_W1, filt_W2, in2f_W, f2out_W, dense_W,
                                    w1t, w2f, whi, wlo);
    k_init_x<<<(BB * AA * FF + 255) / 256, 256, 0, stream>>>(emb, atomic_numbers, x);

    // y0 = x @ in2f_W[0]  (G3-only)
    k_ffn<<<256, 512, 0, stream>>>(x, x, x, yb, out,
                                   whi + 3 * 16384, wlo + 3 * 16384, f2out_b,
                                   whi + 6 * 16384, wlo + 6 * 16384, dense_b,
                                   whi + 0 * 16384, wlo + 0 * 16384,
                                   2);
    for (int l = 0; l < 3; ++l) {
        k_cfconv<<<BB * AA, 512, SMEM_BYTES, stream>>>(
            r_g, cm_g, neighbors,
            w1t + (size_t)l * 128 * 32, filt_b1 + (size_t)l * FF,
            w2f + (size_t)l * 16384, filt_b2 + (size_t)l * FF,
            yb, agg);
        int nextl = (l < 2) ? (l + 1) : 0;
        int mode = 1 | ((l < 2) ? 2 : 0) | ((l == 2) ? 4 : 0);
        k_ffn<<<256, 512, 0, stream>>>(agg, x, x, yb, out,
                                       whi + (3 + l) * 16384, wlo + (3 + l) * 16384, f2out_b + (size_t)l * FF,
                                       whi + (6 + l) * 16384, wlo + (6 + l) * 16384, dense_b + (size_t)l * FF,
                                       whi + nextl * 16384, wlo + nextl * 16384,
                                       mode);
    }
}